// Round 4
// baseline (153.392 us; speedup 1.0000x reference)
//
#include <hip/hip_runtime.h>

// N=524288, D=9, E=2, H=128, M=32, O=2, K=1.
// LAYOUT (confirmed R6): d_in fp32, d_out FP32 (N*2 outputs + 1 loss).
// NUMERICS: pure fp32; accumulation order bit-identical to accepted kernel
// (per-token j-loop strictly sequential; chains independent across tokens).
//
// R4: scalar-stream amortization. Evidence R0-R3: dur tracks per-wave s_load
// dwords per issue-cycle (24dw/48cyc->56-61us; 12dw/48cyc->43.5us), NOT
// occupancy (R3: 2x occupancy, slower) and NOT per-wave ILP (R3 ILP-2 ~= R0).
// => weight delivery via the scalar pipe is the serialization point.
// Fix: 4 tokens/thread (TOKB=1024, grid 512): 48 VALU instr (ILP-4) per
// 16-dword record = 12dw/96cyc, 4x below R0/R3, 2x below R2. Records padded
// 12->16 floats: one 64B line, one s_load_dwordx16 per j (halves requests).
#define NTOK 524288
#define TPB  256
#define TOKB 1024             // tokens per block (4 per thread)
#define NBLK (NTOK / TOKB)    // 512

__device__ __forceinline__ float bf2f(unsigned short u) {
    union { unsigned int i; float f; } v;
    v.i = ((unsigned int)u) << 16;
    return v.f;
}

// input load: raw fp32 (bf16-buffer fallback kept purely as safety)
__device__ __forceinline__ float ldq(const void* p, int i, bool f32) {
    if (f32) return ((const float*)p)[i];
    return bf2f(((const unsigned short*)p)[i]);
}

// ---------------------------------------------------------------------------
// Prep: detect buffer dtype (parallel probe), zero counter, stage w_gate,
// fold W2@Wout (+ b2@Wout + bout), pack per-hidden-unit weights.
// wpack layout (expert-major, PADDED): wpack[e*2048 + j*16 + {0..8:W1col,
// 9:b1, 10..11:W2', 12..15:pad}] — 64B records, line-aligned.
// ---------------------------------------------------------------------------
__global__ void prep_kernel(const void* __restrict__ num_prop,
                            const void* __restrict__ wgate,
                            const void* __restrict__ W1,
                            const void* __restrict__ b1,
                            const void* __restrict__ W2,
                            const void* __restrict__ b2,
                            const void* __restrict__ Wout,
                            const void* __restrict__ bout,
                            unsigned int* __restrict__ cnt1,
                            int* __restrict__ flag,
                            float* __restrict__ bpp,
                            float* __restrict__ wgf,
                            float* __restrict__ wpack)
{
    __shared__ unsigned int bad;
    __shared__ int sflag;
    const int t = threadIdx.x;
    if (t == 0) { bad = 0u; *cnt1 = 0u; }
    __syncthreads();
    if (t < 72) {   // parallel dtype probe
        const unsigned short* u = (const unsigned short*)num_prop;
        int e = (u[t] >> 7) & 0xFF;
        if (e < 64 || e > 191) atomicOr(&bad, 1u);
    }
    __syncthreads();
    if (t == 0) { sflag = (int)bad; *flag = (int)bad; }
    __syncthreads();
    const bool f32 = (sflag != 0);

    if (t < 18) wgf[t] = ldq(wgate, t, f32);        // w_gate [9,2] raw fp32

    if (t < 4) {  // b''[e][o] = sum_m b2[e][m]*Wout[m][o] + bout[o]
        int e = t >> 1, o = t & 1;
        float acc = ldq(bout, o, f32);
        for (int m = 0; m < 32; ++m)
            acc += ldq(b2, e * 32 + m, f32) * ldq(Wout, m * 2 + o, f32);
        bpp[t] = acc;
    }

    const int e = t >> 7;       // 256 threads -> (e, j)
    const int j = t & 127;
    float p0 = 0.f, p1 = 0.f;
    for (int m = 0; m < 32; ++m) {
        float w = ldq(W2, (e * 128 + j) * 32 + m, f32);
        p0 += w * ldq(Wout, m * 2 + 0, f32);
        p1 += w * ldq(Wout, m * 2 + 1, f32);
    }
    float* dst = wpack + e * 2048 + j * 16;
    #pragma unroll
    for (int d = 0; d < 9; ++d)
        dst[d] = ldq(W1, (e * 9 + d) * 128 + j, f32);
    dst[9]  = ldq(b1, e * 128 + j, f32);
    dst[10] = p0;
    dst[11] = p1;
    dst[12] = 0.f; dst[13] = 0.f; dst[14] = 0.f; dst[15] = 0.f;
}

// ---------------------------------------------------------------------------
// Main: 1024 tokens/block, 4/thread. Stage x -> LDS, gate 4 tokens, stable
// partition by expert over 1024 tokens (16 ballot-chunks in token order).
// Thread handles slots 4*tid..4*tid+3 (inside its wave's 256-slot range).
// Expert-uniform waves: per j ONE s_load_dwordx16 record feeds 4 independent
// 9-FMA chains (ILP-4); tail FMAs per token in strict j order (bit-exact).
// Boundary wave (<=1/block) runs dense-both for its 4 tokens. Results
// bounce through LDS to token order -> coalesced float2 stores.
// ---------------------------------------------------------------------------
__global__ __launch_bounds__(TPB, 2)
void moe_main(const void* __restrict__ xg,
              const int* __restrict__ flag,
              const float* __restrict__ wgf,
              const float* __restrict__ bpp,
              const float* __restrict__ wpack,
              unsigned int* __restrict__ cnt1,
              float2* __restrict__ out)
{
    __shared__ __align__(16) float xs[TOKB * 9];   // 36864 B
    __shared__ unsigned short smap[TOKB];          // 2048 B
    __shared__ unsigned int wcnt[16];

    const int tid  = threadIdx.x;
    const int lane = tid & 63;
    const int wave = tid >> 6;

    const bool f32 = (*flag) != 0;
    const int gbase = blockIdx.x * (TOKB * 9);
    if (f32) {
        const float* xf = (const float*)xg;
        #pragma unroll
        for (int i = 0; i < 36; ++i)
            xs[tid + i * TPB] = xf[gbase + tid + i * TPB];   // RAW fp32
    } else {
        const unsigned short* xu = (const unsigned short*)xg;
        for (int i = tid; i < TOKB * 9; i += TPB)
            xs[i] = bf2f(xu[gbase + i]);
    }
    __syncthreads();

    // --- gate 4 tokens (tokens g*256 + tid); chains match accepted kernel ---
    bool e1g[4];
    unsigned long long balg[4];
    #pragma unroll
    for (int g = 0; g < 4; ++g) {
        float l0 = 0.f, l1 = 0.f;
        #pragma unroll
        for (int d = 0; d < 9; ++d) {
            float xv = xs[(g * 256 + tid) * 9 + d];
            l0 = fmaf(xv, wgf[d * 2 + 0], l0);
            l1 = fmaf(xv, wgf[d * 2 + 1], l1);
        }
        e1g[g] = l1 > l0;          // tie -> expert 0 (stable top_k)
        balg[g] = __ballot(e1g[g]);
        if (lane == 0) wcnt[g * 4 + wave] = (unsigned int)__popcll(balg[g]);
    }
    __syncthreads();

    // --- stable partition over 1024 tokens (chunk c = g*4+wave, token order) ---
    int pres[16]; int run = 0;
    #pragma unroll
    for (int c = 0; c < 16; ++c) { pres[c] = run; run += (int)wcnt[c]; }
    const int n1 = run;
    const int n0 = TOKB - n1;
    const unsigned long long below = (1ull << lane) - 1ull;
    #pragma unroll
    for (int g = 0; g < 4; ++g) {
        const int tok = g * 256 + tid;
        const int pr  = pres[g * 4 + wave] + (int)__popcll(balg[g] & below);
        const int slot = e1g[g] ? (n0 + pr) : (tok - pr);
        smap[slot] = (unsigned short)tok;
    }
    if (tid == 0) atomicAdd(cnt1, (unsigned int)n1);
    __syncthreads();

    // --- this thread processes slots 4*tid .. 4*tid+3 ---
    const int s0 = tid * 4;
    const int tk0 = (int)smap[s0 + 0], tk1 = (int)smap[s0 + 1];
    const int tk2 = (int)smap[s0 + 2], tk3 = (int)smap[s0 + 3];
    float x0[9], x1[9], x2[9], x3[9];
    #pragma unroll
    for (int d = 0; d < 9; ++d) {
        x0[d] = xs[tk0 * 9 + d];
        x1[d] = xs[tk1 * 9 + d];
        x2[d] = xs[tk2 * 9 + d];
        x3[d] = xs[tk3 * 9 + d];
    }

    // wave's slot range = [wave*256, wave*256+256); scalarized uniformity test
    const int wslot = __builtin_amdgcn_readfirstlane(wave) << 8;
    const int n0u   = __builtin_amdgcn_readfirstlane(n0);

    float2 r0v, r1v, r2v, r3v;
    if (n0u <= wslot || n0u >= wslot + 256) {
        // expert-uniform wave: one 64B record (s_load_dwordx16) per j,
        // 4 independent chains; per-token accumulation in strict j order.
        const int ew = (n0u <= wslot) ? 1 : 0;
        const float* wp = wpack + ew * 2048;
        const float b0 = bpp[ew * 2 + 0], b1v = bpp[ew * 2 + 1];
        float a00 = b0, a01 = b1v, a10 = b0, a11 = b1v;
        float a20 = b0, a21 = b1v, a30 = b0, a31 = b1v;
        #pragma unroll 2
        for (int j = 0; j < 128; ++j) {
            const float* r = wp + j * 16;   // uniform index -> s_load x16
            float h0 = r[9], h1 = r[9], h2 = r[9], h3 = r[9];
            #pragma unroll
            for (int d = 0; d < 9; ++d) {
                const float w = r[d];
                h0 = fmaf(x0[d], w, h0);
                h1 = fmaf(x1[d], w, h1);
                h2 = fmaf(x2[d], w, h2);
                h3 = fmaf(x3[d], w, h3);
            }
            h0 = fmaxf(h0, 0.f); h1 = fmaxf(h1, 0.f);
            h2 = fmaxf(h2, 0.f); h3 = fmaxf(h3, 0.f);
            const float wa = r[10], wb = r[11];
            a00 = fmaf(h0, wa, a00); a01 = fmaf(h0, wb, a01);
            a10 = fmaf(h1, wa, a10); a11 = fmaf(h1, wb, a11);
            a20 = fmaf(h2, wa, a20); a21 = fmaf(h2, wb, a21);
            a30 = fmaf(h3, wa, a30); a31 = fmaf(h3, wb, a31);
        }
        r0v.x = a00; r0v.y = a01; r1v.x = a10; r1v.y = a11;
        r2v.x = a20; r2v.y = a21; r3v.x = a30; r3v.y = a31;
    } else {
        // boundary wave (<=1/block): dense both experts, select per slot
        float A0[4], A1[4], A2[4], A3[4];   // per token k: [e0o0,e0o1,e1o0,e1o1]
        #pragma unroll
        for (int k = 0; k < 4; ++k) { A0[k] = bpp[0]; A1[k] = bpp[1]; A2[k] = bpp[2]; A3[k] = bpp[3]; }
        for (int j = 0; j < 128; ++j) {
            const float* p0 = wpack + j * 16;
            const float* p1 = wpack + 2048 + j * 16;
            float h00 = p0[9], h01 = p1[9];
            float h10 = p0[9], h11 = p1[9];
            float h20 = p0[9], h21 = p1[9];
            float h30 = p0[9], h31 = p1[9];
            #pragma unroll
            for (int d = 0; d < 9; ++d) {
                const float w0 = p0[d], w1 = p1[d];
                h00 = fmaf(x0[d], w0, h00); h01 = fmaf(x0[d], w1, h01);
                h10 = fmaf(x1[d], w0, h10); h11 = fmaf(x1[d], w1, h11);
                h20 = fmaf(x2[d], w0, h20); h21 = fmaf(x2[d], w1, h21);
                h30 = fmaf(x3[d], w0, h30); h31 = fmaf(x3[d], w1, h31);
            }
            h00 = fmaxf(h00, 0.f); h01 = fmaxf(h01, 0.f);
            h10 = fmaxf(h10, 0.f); h11 = fmaxf(h11, 0.f);
            h20 = fmaxf(h20, 0.f); h21 = fmaxf(h21, 0.f);
            h30 = fmaxf(h30, 0.f); h31 = fmaxf(h31, 0.f);
            const float wa0 = p0[10], wb0 = p0[11], wa1 = p1[10], wb1 = p1[11];
            A0[0] = fmaf(h00, wa0, A0[0]); A1[0] = fmaf(h00, wb0, A1[0]);
            A2[0] = fmaf(h01, wa1, A2[0]); A3[0] = fmaf(h01, wb1, A3[0]);
            A0[1] = fmaf(h10, wa0, A0[1]); A1[1] = fmaf(h10, wb0, A1[1]);
            A2[1] = fmaf(h11, wa1, A2[1]); A3[1] = fmaf(h11, wb1, A3[1]);
            A0[2] = fmaf(h20, wa0, A0[2]); A1[2] = fmaf(h20, wb0, A1[2]);
            A2[2] = fmaf(h21, wa1, A2[2]); A3[2] = fmaf(h21, wb1, A3[2]);
            A0[3] = fmaf(h30, wa0, A0[3]); A1[3] = fmaf(h30, wb0, A1[3]);
            A2[3] = fmaf(h31, wa1, A2[3]); A3[3] = fmaf(h31, wb1, A3[3]);
        }
        const bool e0s = (s0 + 0) >= n0u, e1s = (s0 + 1) >= n0u;
        const bool e2s = (s0 + 2) >= n0u, e3s = (s0 + 3) >= n0u;
        r0v.x = e0s ? A2[0] : A0[0]; r0v.y = e0s ? A3[0] : A1[0];
        r1v.x = e1s ? A2[1] : A0[1]; r1v.y = e1s ? A3[1] : A1[1];
        r2v.x = e2s ? A2[2] : A0[2]; r2v.y = e2s ? A3[2] : A1[2];
        r3v.x = e3s ? A2[3] : A0[3]; r3v.y = e3s ? A3[3] : A1[3];
    }

    // --- bounce through LDS to token order; coalesced float2 stores ---
    __syncthreads();                        // all xs reads complete
    float2* ob = (float2*)xs;               // 1024 float2 = 8192 floats < xs
    ob[tk0] = r0v; ob[tk1] = r1v; ob[tk2] = r2v; ob[tk3] = r3v;
    __syncthreads();
    const int obase = blockIdx.x * TOKB;
    #pragma unroll
    for (int g = 0; g < 4; ++g)
        out[obase + g * 256 + tid] = ob[g * 256 + tid];
}

// Loss: gates one-hot value-1.0 -> importance == load == counts.
// cv^2 ddof=1: var=(c0-c1)^2/2, mean=N/2; loss = 0.01*2*cv^2 (~1e-9).
__global__ void finalize_kernel(const unsigned int* __restrict__ cnt1,
                                float* __restrict__ loss_out)
{
    double c1 = (double)(*cnt1);
    double c0 = (double)NTOK - c1;
    double diff = c0 - c1;
    double mean = (double)NTOK * 0.5;
    double var  = 0.5 * diff * diff;
    double cv2  = var / (mean * mean + 1e-10);
    *loss_out = (float)(0.02 * cv2);
}

extern "C" void kernel_launch(void* const* d_in, const int* in_sizes, int n_in,
                              void* d_out, int out_size, void* d_ws, size_t ws_size,
                              hipStream_t stream) {
    const void* num_prop = d_in[0]; // [N,9] fp32
    // d_in[1] = cat_prop (unused)
    const void* w_gate   = d_in[2]; // [9,2]
    const void* W1       = d_in[3]; // [2,9,128]
    const void* b1       = d_in[4]; // [2,128]
    const void* W2       = d_in[5]; // [2,128,32]
    const void* b2       = d_in[6]; // [2,32]
    const void* Wout     = d_in[7]; // [32,2]
    const void* bout     = d_in[8]; // [2]
    // d_in[9] = k (==1)

    char* ws = (char*)d_ws;
    unsigned int* cnt1 = (unsigned int*)ws;          // @0
    int* flag          = (int*)(ws + 8);             // @8
    float* bpp         = (float*)(ws + 16);          // 4 f
    float* wgf         = (float*)(ws + 64);          // 18 f
    float* wpack       = (float*)(ws + 192);         // 4096 f (padded 64B records)

    float*  outf = (float*)d_out;                    // FP32: N*2 + loss
    float2* out2 = (float2*)d_out;

    hipLaunchKernelGGL(prep_kernel, dim3(1), dim3(256), 0, stream,
                       num_prop, w_gate, W1, b1, W2, b2, Wout, bout,
                       cnt1, flag, bpp, wgf, wpack);
    hipLaunchKernelGGL(moe_main, dim3(NBLK), dim3(TPB), 0, stream,
                       num_prop, flag, wgf, bpp, wpack, cnt1, out2);
    hipLaunchKernelGGL(finalize_kernel, dim3(1), dim3(1), 0, stream,
                       cnt1, outf + (size_t)NTOK * 2);
}

// Round 5
// 127.842 us; speedup vs baseline: 1.1999x; 1.1999x over previous
//
#include <hip/hip_runtime.h>

// N=524288, D=9, E=2, H=128, M=32, O=2, K=1.
// LAYOUT (confirmed R6): d_in fp32, d_out FP32 (N*2 outputs + 1 loss).
// NUMERICS: pure fp32; per-token fmaf chains identical to accepted kernel.
//
// R5: weight delivery moved from the SCALAR pipe to LDS BROADCAST.
// Evidence R0-R4: per-wave j-latency ~1160 cyc vs 96 issue (R4), and R3
// reads HALF R0's scalar dwords yet is slower => stall is per-s_load-use
// latency (SMEM returns out-of-order -> lgkmcnt(0) full drains, prefetch
// depth ~1), not scalar BW/request count. DS returns IN-ORDER -> counted
// lgkmcnt waits -> weight fetch finally pipelines; uniform-address
// ds_read_b128 broadcasts conflict-free. Config otherwise = R2 (best:
// 2 tok/thread, TOKB=512, grid 1024), arithmetic bit-identical.
#define NTOK 524288
#define TPB  256
#define TOKB 512              // tokens per block (2 per thread)
#define NBLK (NTOK / TOKB)    // 1024

__device__ __forceinline__ float bf2f(unsigned short u) {
    union { unsigned int i; float f; } v;
    v.i = ((unsigned int)u) << 16;
    return v.f;
}

// input load: raw fp32 (bf16-buffer fallback kept purely as safety)
__device__ __forceinline__ float ldq(const void* p, int i, bool f32) {
    if (f32) return ((const float*)p)[i];
    return bf2f(((const unsigned short*)p)[i]);
}

// ---------------------------------------------------------------------------
// Prep: detect buffer dtype (parallel probe), zero counter, stage w_gate,
// fold W2@Wout (+ b2@Wout + bout), pack per-hidden-unit weights.
// wpack layout (expert-major): wpack[e*1536 + j*12 + {0..8:W1col, 9:b1,
// 10..11:W2'}] — 48B records, 16B-aligned.
// ---------------------------------------------------------------------------
__global__ void prep_kernel(const void* __restrict__ num_prop,
                            const void* __restrict__ wgate,
                            const void* __restrict__ W1,
                            const void* __restrict__ b1,
                            const void* __restrict__ W2,
                            const void* __restrict__ b2,
                            const void* __restrict__ Wout,
                            const void* __restrict__ bout,
                            unsigned int* __restrict__ cnt1,
                            int* __restrict__ flag,
                            float* __restrict__ bpp,
                            float* __restrict__ wgf,
                            float* __restrict__ wpack)
{
    __shared__ unsigned int bad;
    __shared__ int sflag;
    const int t = threadIdx.x;
    if (t == 0) { bad = 0u; *cnt1 = 0u; }
    __syncthreads();
    if (t < 72) {   // parallel dtype probe
        const unsigned short* u = (const unsigned short*)num_prop;
        int e = (u[t] >> 7) & 0xFF;
        if (e < 64 || e > 191) atomicOr(&bad, 1u);
    }
    __syncthreads();
    if (t == 0) { sflag = (int)bad; *flag = (int)bad; }
    __syncthreads();
    const bool f32 = (sflag != 0);

    if (t < 18) wgf[t] = ldq(wgate, t, f32);        // w_gate [9,2] raw fp32

    if (t < 4) {  // b''[e][o] = sum_m b2[e][m]*Wout[m][o] + bout[o]
        int e = t >> 1, o = t & 1;
        float acc = ldq(bout, o, f32);
        for (int m = 0; m < 32; ++m)
            acc += ldq(b2, e * 32 + m, f32) * ldq(Wout, m * 2 + o, f32);
        bpp[t] = acc;
    }

    const int e = t >> 7;       // 256 threads -> (e, j)
    const int j = t & 127;
    float p0 = 0.f, p1 = 0.f;
    for (int m = 0; m < 32; ++m) {
        float w = ldq(W2, (e * 128 + j) * 32 + m, f32);
        p0 += w * ldq(Wout, m * 2 + 0, f32);
        p1 += w * ldq(Wout, m * 2 + 1, f32);
    }
    float* dst = wpack + e * 1536 + j * 12;
    #pragma unroll
    for (int d = 0; d < 9; ++d)
        dst[d] = ldq(W1, (e * 9 + d) * 128 + j, f32);
    dst[9]  = ldq(b1, e * 128 + j, f32);
    dst[10] = p0;
    dst[11] = p1;
}

// ---------------------------------------------------------------------------
// Main: 512 tokens/block, 2/thread (R2 config). Stage weights (12KB) + x
// (18KB) into LDS. Gate, stable partition by expert (ballot + 8-chunk
// prefix). Expert-uniform waves: per j, 3 uniform-address ds_read_b128
// (LDS broadcast, in-order, counted lgkmcnt) feed two independent token
// chains (ILP-2). Boundary wave (<=1/block) reads both experts' records
// from LDS. Results bounce through LDS to token order -> coalesced stores.
// LDS total ~31.8KB -> 5 blocks/CU (20 waves/CU).
// ---------------------------------------------------------------------------
__global__ __launch_bounds__(TPB, 5)
void moe_main(const void* __restrict__ xg,
              const int* __restrict__ flag,
              const float* __restrict__ wgf,
              const float* __restrict__ bpp,
              const float* __restrict__ wpack,
              unsigned int* __restrict__ cnt1,
              float2* __restrict__ out)
{
    __shared__ __align__(16) float xs[TOKB * 9];   // 18432 B
    __shared__ __align__(16) float wsm[3072];      // 12288 B (both experts)
    __shared__ unsigned short smap[TOKB];          // 1024 B
    __shared__ unsigned int wcnt[8];

    const int tid  = threadIdx.x;
    const int lane = tid & 63;
    const int wave = tid >> 6;

    const bool f32 = (*flag) != 0;
    const int gbase = blockIdx.x * (TOKB * 9);

    // stage weights: 12 coalesced floats per thread
    #pragma unroll
    for (int i = 0; i < 12; ++i)
        wsm[tid + i * TPB] = wpack[tid + i * TPB];

    if (f32) {
        const float* xf = (const float*)xg;
        #pragma unroll
        for (int i = 0; i < 18; ++i)
            xs[tid + i * TPB] = xf[gbase + tid + i * TPB];   // RAW fp32
    } else {
        const unsigned short* xu = (const unsigned short*)xg;
        for (int i = tid; i < TOKB * 9; i += TPB)
            xs[i] = bf2f(xu[gbase + i]);
    }
    __syncthreads();

    // --- gate both tokens (same fmaf chains as accepted kernel) ---
    float l0A = 0.f, l1A = 0.f, l0B = 0.f, l1B = 0.f;
    #pragma unroll
    for (int d = 0; d < 9; ++d) {
        const float wa = wgf[d * 2 + 0], wb = wgf[d * 2 + 1];
        const float xA = xs[tid * 9 + d];
        const float xB = xs[(tid + 256) * 9 + d];
        l0A = fmaf(xA, wa, l0A); l1A = fmaf(xA, wb, l1A);
        l0B = fmaf(xB, wa, l0B); l1B = fmaf(xB, wb, l1B);
    }
    const bool e1A = l1A > l0A;   // tie -> expert 0 (stable top_k)
    const bool e1B = l1B > l0B;

    // --- stable partition over 512 tokens: chunk order = token order ---
    unsigned long long balA = __ballot(e1A);
    unsigned long long balB = __ballot(e1B);
    if (lane == 0) {
        wcnt[wave]     = (unsigned int)__popcll(balA);   // tokens wave*64..
        wcnt[4 + wave] = (unsigned int)__popcll(balB);   // tokens 256+wave*64..
    }
    __syncthreads();
    int pres[8]; int run = 0;
    #pragma unroll
    for (int c = 0; c < 8; ++c) { pres[c] = run; run += (int)wcnt[c]; }
    const int n1 = run;
    const int n0 = TOKB - n1;
    const unsigned long long below = (1ull << lane) - 1ull;
    const int prA = pres[wave]     + (int)__popcll(balA & below);
    const int prB = pres[4 + wave] + (int)__popcll(balB & below);
    const int slotA = e1A ? (n0 + prA) : (tid - prA);
    const int slotB = e1B ? (n0 + prB) : (tid + 256 - prB);
    smap[slotA] = (unsigned short)tid;
    smap[slotB] = (unsigned short)(tid + 256);
    __syncthreads();

    // --- this thread processes slots 2*tid, 2*tid+1 ---
    const int sA = tid * 2, sB = sA + 1;
    const int tA = (int)smap[sA], tB = (int)smap[sB];
    float xa[9], xb[9];
    #pragma unroll
    for (int d = 0; d < 9; ++d) { xa[d] = xs[tA * 9 + d]; xb[d] = xs[tB * 9 + d]; }

    // scalarize uniformity test: wave's slot range = [wave*128, wave*128+128)
    const int wbase = __builtin_amdgcn_readfirstlane(tid & 192) << 1;
    const int n0u   = __builtin_amdgcn_readfirstlane(n0);

    float2 ra, rb;
    if (n0u <= wbase || n0u >= wbase + 128) {
        // expert-uniform wave: per j, one 12-dword LDS record (3x broadcast
        // ds_read_b128) -> two independent token chains (ILP-2).
        const int ew = (n0u <= wbase) ? 1 : 0;
        const float* wp = wsm + ew * 1536;
        float a0 = bpp[ew * 2 + 0], a1 = bpp[ew * 2 + 1];
        float c0 = a0, c1 = a1;
        #pragma unroll 2
        for (int j = 0; j < 128; ++j) {
            const float* r = wp + j * 12;   // uniform LDS addr -> broadcast
            float hA = r[9], hB = r[9];
            #pragma unroll
            for (int d = 0; d < 9; ++d) {
                hA = fmaf(xa[d], r[d], hA);
                hB = fmaf(xb[d], r[d], hB);
            }
            hA = fmaxf(hA, 0.f); hB = fmaxf(hB, 0.f);
            a0 = fmaf(hA, r[10], a0); a1 = fmaf(hA, r[11], a1);
            c0 = fmaf(hB, r[10], c0); c1 = fmaf(hB, r[11], c1);
        }
        ra.x = a0; ra.y = a1; rb.x = c0; rb.y = c1;
    } else {
        // boundary wave (<=1/block): dense both experts, select per token
        const bool eA = (sA >= n0u), eB = (sB >= n0u);
        float aA0 = bpp[0], aA1 = bpp[1], aA2 = bpp[2], aA3 = bpp[3];
        float aB0 = bpp[0], aB1 = bpp[1], aB2 = bpp[2], aB3 = bpp[3];
        #pragma unroll 2
        for (int j = 0; j < 128; ++j) {
            const float* r0 = wsm + j * 12;
            const float* r1 = wsm + 1536 + j * 12;
            float hA0 = r0[9], hA1 = r1[9], hB0 = r0[9], hB1 = r1[9];
            #pragma unroll
            for (int d = 0; d < 9; ++d) {
                hA0 = fmaf(xa[d], r0[d], hA0);
                hA1 = fmaf(xa[d], r1[d], hA1);
                hB0 = fmaf(xb[d], r0[d], hB0);
                hB1 = fmaf(xb[d], r1[d], hB1);
            }
            hA0 = fmaxf(hA0, 0.f); hA1 = fmaxf(hA1, 0.f);
            hB0 = fmaxf(hB0, 0.f); hB1 = fmaxf(hB1, 0.f);
            aA0 = fmaf(hA0, r0[10], aA0); aA1 = fmaf(hA0, r0[11], aA1);
            aA2 = fmaf(hA1, r1[10], aA2); aA3 = fmaf(hA1, r1[11], aA3);
            aB0 = fmaf(hB0, r0[10], aB0); aB1 = fmaf(hB0, r0[11], aB1);
            aB2 = fmaf(hB1, r1[10], aB2); aB3 = fmaf(hB1, r1[11], aB3);
        }
        ra.x = eA ? aA2 : aA0; ra.y = eA ? aA3 : aA1;
        rb.x = eB ? aB2 : aB0; rb.y = eB ? aB3 : aB1;
    }

    // --- bounce through LDS to token order; coalesced float2 stores ---
    __syncthreads();                        // all xs reads complete
    float2* ob = (float2*)xs;
    ob[tA] = ra;
    ob[tB] = rb;
    __syncthreads();
    const int obase = blockIdx.x * TOKB;
    out[obase + tid]       = ob[tid];
    out[obase + 256 + tid] = ob[256 + tid];
    if (tid == 0) atomicAdd(cnt1, (unsigned int)n1);
}

// Loss: gates one-hot value-1.0 -> importance == load == counts.
// cv^2 ddof=1: var=(c0-c1)^2/2, mean=N/2; loss = 0.01*2*cv^2 (~1e-9).
__global__ void finalize_kernel(const unsigned int* __restrict__ cnt1,
                                float* __restrict__ loss_out)
{
    double c1 = (double)(*cnt1);
    double c0 = (double)NTOK - c1;
    double diff = c0 - c1;
    double mean = (double)NTOK * 0.5;
    double var  = 0.5 * diff * diff;
    double cv2  = var / (mean * mean + 1e-10);
    *loss_out = (float)(0.02 * cv2);
}

extern "C" void kernel_launch(void* const* d_in, const int* in_sizes, int n_in,
                              void* d_out, int out_size, void* d_ws, size_t ws_size,
                              hipStream_t stream) {
    const void* num_prop = d_in[0]; // [N,9] fp32
    // d_in[1] = cat_prop (unused)
    const void* w_gate   = d_in[2]; // [9,2]
    const void* W1       = d_in[3]; // [2,9,128]
    const void* b1       = d_in[4]; // [2,128]
    const void* W2       = d_in[5]; // [2,128,32]
    const void* b2       = d_in[6]; // [2,32]
    const void* Wout     = d_in[7]; // [32,2]
    const void* bout     = d_in[8]; // [2]
    // d_in[9] = k (==1)

    char* ws = (char*)d_ws;
    unsigned int* cnt1 = (unsigned int*)ws;          // @0
    int* flag          = (int*)(ws + 8);             // @8
    float* bpp         = (float*)(ws + 16);          // 4 f
    float* wgf         = (float*)(ws + 64);          // 18 f
    float* wpack       = (float*)(ws + 192);         // 3072 f (expert-major)

    float*  outf = (float*)d_out;                    // FP32: N*2 + loss
    float2* out2 = (float2*)d_out;

    hipLaunchKernelGGL(prep_kernel, dim3(1), dim3(256), 0, stream,
                       num_prop, w_gate, W1, b1, W2, b2, Wout, bout,
                       cnt1, flag, bpp, wgf, wpack);
    hipLaunchKernelGGL(moe_main, dim3(NBLK), dim3(TPB), 0, stream,
                       num_prop, flag, wgf, bpp, wpack, cnt1, out2);
    hipLaunchKernelGGL(finalize_kernel, dim3(1), dim3(1), 0, stream,
                       cnt1, outf + (size_t)NTOK * 2);
}